// Round 2
// baseline (634.390 us; speedup 1.0000x reference)
//
#include <hip/hip_runtime.h>

#define NN 50000
#define NPAD 50048   // rows padded to multiple of 64 for MFMA tiles
#define NE 800000
#define FIN 64
#define H 128
#define NG 16
#define NPART 64         // private pooled-accumulator copies (atomic spreading)
#define NBUCK 196        // buckets of 256 dst nodes
#define BUCK_CAP 4800    // edges per bucket capacity (expected 4096 +- 64)
#define FILLA_BLOCKS 512
#define FILLA_CHUNK 1563  // ceil(NE / FILLA_BLOCKS)
#define CHUNK_U 16       // uints per node per feature-chunk (32 feats)
#define DUMMY NN         // zero pad row used for CSR padding
#define AGG_CH (NPAD / 64) // 782 blocks per chunk (64 nodes/block)
#define ZERO_I4 32768    // int4s to zero: poolpart = 131072 ints
#define PREP_ITEMS (NPAD * FIN + H * FIN + 3 * H * H + ZERO_I4)
#define PREP_BLOCKS ((PREP_ITEMS + 255) / 256)

typedef __bf16 bf16x8 __attribute__((ext_vector_type(8)));
typedef float f32x4 __attribute__((ext_vector_type(4)));
typedef float f32x2 __attribute__((ext_vector_type(2)));

// ---- helpers ----
__device__ inline unsigned short bf16r(float x) {
    unsigned int u = __float_as_uint(x);
    return (unsigned short)((u + 0x7fffu + ((u >> 16) & 1u)) >> 16);
}
__device__ inline unsigned int pack_bf16x2(float a, float b) {
    return (unsigned int)bf16r(a) | ((unsigned int)bf16r(b) << 16);
}
__device__ inline float bf_lo(unsigned int u) { return __uint_as_float(u << 16); }
__device__ inline float bf_hi(unsigned int u) { return __uint_as_float(u & 0xffff0000u); }

// packed fp32 add: acc(pair) += {lo(u), hi(u)}
__device__ inline void pkadd(f32x2& a, unsigned int u) {
    f32x2 p;
    p.x = bf_lo(u);
    p.y = bf_hi(u);
    asm("v_pk_add_f32 %0, %1, %0" : "+v"(a) : "v"(p));
}

// ====== fillA + prep merged: blocks [0,512) bucket edges; rest convert x/W + zero pool ======
__global__ __launch_bounds__(256) void fillA_prep_kernel(const int* __restrict__ ei,
                                                         int* __restrict__ gcount,
                                                         unsigned int* __restrict__ ebuf,
                                                         const float* __restrict__ x,
                                                         const float* __restrict__ W1,
                                                         const float* __restrict__ W2,
                                                         const float* __restrict__ W3,
                                                         const float* __restrict__ W4,
                                                         unsigned short* __restrict__ xb,
                                                         unsigned short* __restrict__ Wt1,
                                                         unsigned short* __restrict__ Wt2,
                                                         unsigned short* __restrict__ Wt3,
                                                         unsigned short* __restrict__ Wt4,
                                                         int4* __restrict__ zbuf) {
    const int t = threadIdx.x;
    if (blockIdx.x >= FILLA_BLOCKS) {
        // ---- prep part ----
        int e = (blockIdx.x - FILLA_BLOCKS) * 256 + t;
        if (e < NPAD * FIN) {
            int n = e >> 6, k = e & 63;
            unsigned short v = (n < NN) ? bf16r(x[n * FIN + k]) : (unsigned short)0;
            xb[(size_t)(k >> 5) * (NPAD * 32) + n * 32 + (k & 31)] = v;
            return;
        }
        int tt = e - NPAD * FIN;
        if (tt < H * FIN) {
            int n = tt / FIN, k = tt % FIN;
            Wt1[tt] = bf16r(W1[k * H + n]);
            return;
        }
        int u = tt - H * FIN;
        if (u < 3 * H * H) {
            const float* W = W2;
            unsigned short* Wt = Wt2;
            if (u >= 2 * H * H) { W = W4; Wt = Wt4; u -= 2 * H * H; }
            else if (u >= H * H) { W = W3; Wt = Wt3; u -= H * H; }
            int n = u / H, k = u % H;
            Wt[u] = bf16r(W[k * H + n]);
            return;
        }
        int z = u - 3 * H * H;
        if (z < ZERO_I4) zbuf[z] = make_int4(0, 0, 0, 0);  // zero pool partials
        return;
    }
    // ---- fillA part: histogram into 196 buckets of 256 nodes ----
    __shared__ int hist[256];
    __shared__ int base[256];
    hist[t] = 0;
    __syncthreads();
    const int e0 = blockIdx.x * FILLA_CHUNK;
    const int e1 = min(e0 + FILLA_CHUNK, NE);
    for (int e = e0 + t; e < e1; e += 256)
        atomicAdd(&hist[ei[NE + e] >> 8], 1);
    __syncthreads();
    {
        int h = hist[t];
        base[t] = h ? atomicAdd(&gcount[t], h) : 0;
    }
    __syncthreads();
    for (int e = e0 + t; e < e1; e += 256) {
        int d = ei[NE + e];
        int s = ei[e];
        int b = d >> 8;
        int pos = atomicAdd(&base[b], 1);
        ebuf[b * BUCK_CAP + pos] = (unsigned int)s | ((unsigned int)d << 16);
    }
}

// fillB (fused hist+scan+scatter), 196 blocks, 1 node per thread.
// Also: degree-class ranking (for divergence-free agg) + per-graph node counts.
__global__ __launch_bounds__(256) void fillB_kernel(const unsigned int* __restrict__ ebuf,
                                                    const int* __restrict__ gcount,
                                                    int* __restrict__ galloc,
                                                    int* __restrict__ classCnt,
                                                    int* __restrict__ pcnt,
                                                    const int* __restrict__ batch,
                                                    int2* __restrict__ rowse,
                                                    float* __restrict__ dinv,
                                                    int* __restrict__ nclass,
                                                    unsigned short* __restrict__ csr) {
    __shared__ int lh[256];
    __shared__ int lsum[256];
    __shared__ int lcur[256];
    __shared__ int lcls[16];
    __shared__ int lclsbase[16];
    __shared__ int lgc[16];
    __shared__ int base_s;
    const int b = blockIdx.x, t = threadIdx.x;
    const int n0 = b * 256;
    lh[t] = 0;
    if (t < 16) { lcls[t] = 0; lgc[t] = 0; }
    __syncthreads();
    const int ne = gcount[b];
    const unsigned int* __restrict__ eb = ebuf + b * BUCK_CAP;
    for (int i = t; i < ne; i += 256)
        atomicAdd(&lh[(int)(eb[i] >> 16) - n0], 1);
    __syncthreads();
    const int c = lh[t];
    const int p = (c + 7) & ~7;
    const int n = n0 + t;
    int cls = 0, lrank = 0;
    if (n < NN) {
        cls = min(p >> 3, 15);
        lrank = atomicAdd(&lcls[cls], 1);
        atomicAdd(&lgc[batch[n]], 1);
    }
    lsum[t] = p;
    __syncthreads();
    if (t < 16) {
        lclsbase[t] = lcls[t] ? atomicAdd(&classCnt[t], lcls[t]) : 0;
        if (lgc[t]) atomicAdd(&pcnt[t], lgc[t]);
    }
    for (int off = 1; off < 256; off <<= 1) {
        int u = (t >= off) ? lsum[t - off] : 0;
        __syncthreads();
        lsum[t] += u;
        __syncthreads();
    }
    if (t == 255) base_s = atomicAdd(galloc, lsum[255]);
    const int excl = t ? lsum[t - 1] : 0;
    __syncthreads();
    const int st = base_s + excl;
    if (n < NN) {
        rowse[n] = make_int2(st, st + p);
        dinv[n] = rsqrtf((float)c + 1.0f);  // +1 self-loop
        nclass[n] = (lclsbase[cls] + lrank) | (cls << 24);
    } else if (n < NPAD) {
        rowse[n] = make_int2(0, 0);
        dinv[n] = 0.0f;
    }
    lcur[t] = st;
    __syncthreads();
    for (int i = t; i < ne; i += 256) {
        unsigned int u = eb[i];
        int pos = atomicAdd(&lcur[(int)(u >> 16) - n0], 1);
        csr[pos] = (unsigned short)(u & 0xFFFFu);
    }
    __syncthreads();
    for (int k = st + c; k < st + p; k++) csr[k] = (unsigned short)DUMMY;
}

// ===== MFMA GEMM (chunked in/out): hw' = (h @ W) * dinv[row], bf16 out =====
// PERM=true (layer 1): spare lanes build the degree-sorted node permutation.
#define LSTRIDE 130
template <int K, bool PERM>
__global__ __launch_bounds__(256) void gemm_mfma_kernel(const unsigned short* __restrict__ hb,
                                                        const unsigned short* __restrict__ Wt,
                                                        const float* __restrict__ dinv,
                                                        const int* __restrict__ nclass,
                                                        const int* __restrict__ classCnt,
                                                        int* __restrict__ perm,
                                                        unsigned int* __restrict__ outu) {
    __shared__ float ls[64 * LSTRIDE];  // ~33 KB
    const int wave = threadIdx.x >> 6, lane = threadIdx.x & 63;
    const int m15 = lane & 15, quad = lane >> 4;
    const int row0 = blockIdx.x * 64;
    const int arow = row0 + wave * 16 + m15;

    if (PERM && threadIdx.x < 64) {
        int n = row0 + threadIdx.x;
        if (n < NN) {
            int pk = nclass[n];
            int cls = pk >> 24, rk = pk & 0xFFFFFF;
            int base = 0;
#pragma unroll
            for (int j = 0; j < 16; j++) base += (j < cls) ? classCnt[j] : 0;
            perm[base + rk] = n;
        } else {
            perm[n] = n;  // pad slots map to themselves
        }
    }

    bf16x8 a[K / 32];
#pragma unroll
    for (int ks = 0; ks < K / 32; ks++)
        a[ks] = *(const bf16x8*)&hb[(size_t)ks * (NPAD * 32) + arow * 32 + quad * 8];

    const int lrow = wave * 16 + quad * 4;
    float dv[4];
#pragma unroll
    for (int r = 0; r < 4; r++) dv[r] = dinv[row0 + lrow + r];

#pragma unroll
    for (int ct = 0; ct < 8; ct++) {
        f32x4 acc = {0.f, 0.f, 0.f, 0.f};
#pragma unroll
        for (int ks = 0; ks < K / 32; ks++) {
            bf16x8 b = *(const bf16x8*)&Wt[(ct * 16 + m15) * K + ks * 32 + quad * 8];
            acc = __builtin_amdgcn_mfma_f32_16x16x32_bf16(a[ks], b, acc, 0, 0, 0);
        }
#pragma unroll
        for (int r = 0; r < 4; r++)
            ls[(lrow + r) * LSTRIDE + ct * 16 + m15] = acc[r] * dv[r];
    }
    __syncthreads();

#pragma unroll
    for (int k = 0; k < 4; k++) {
        int idx = threadIdx.x + 256 * k;
        int c = idx >> 8, row = (idx >> 2) & 63, q = idx & 3;
        const float* p = &ls[row * LSTRIDE + c * 32 + q * 8];
        uint4 o;
        o.x = pack_bf16x2(p[0], p[1]);
        o.y = pack_bf16x2(p[2], p[3]);
        o.z = pack_bf16x2(p[4], p[5]);
        o.w = pack_bf16x2(p[6], p[7]);
        *(uint4*)&outu[(size_t)c * (NPAD * CHUNK_U) + (size_t)(row0 + row) * CHUNK_U + q * 4] = o;
    }
}

// ====== feature-chunked gather aggregation over degree-sorted slots ======
// 4 lanes per node, uint4 gathers, v_pk_add_f32 accumulation.
// MODE 0: relu(x*dinv + bias) -> bf16 store.   MODE 1: pool atomics (layer 4).
template <int MODE>
__global__ __launch_bounds__(256) void agg_kernel(const unsigned int* __restrict__ hwc,
                                                  const int2* __restrict__ rowse,
                                                  const unsigned short* __restrict__ csr,
                                                  const float* __restrict__ dinv,
                                                  const float* __restrict__ bias,
                                                  const int* __restrict__ perm,
                                                  const int* __restrict__ batch,
                                                  float* __restrict__ poolpart,
                                                  unsigned int* __restrict__ outc) {
    const int chunk = blockIdx.x / AGG_CH;
    const int nb = blockIdx.x % AGG_CH;
    const int g = threadIdx.x & 3;               // lane's uint-quad within the chunk
    const int slot = nb * 64 + (threadIdx.x >> 2);
    const int n = perm[slot];
    if (MODE == 1 && n >= NN) return;            // pads contribute nothing to pooling
    const int u0 = g * 4;
    const unsigned int* __restrict__ slice = hwc + (size_t)chunk * (NPAD * CHUNK_U);

    uint4 sv = *(const uint4*)&slice[n * CHUNK_U + u0];  // self-loop term
    f32x2 a0 = {bf_lo(sv.x), bf_hi(sv.x)};
    f32x2 a1 = {bf_lo(sv.y), bf_hi(sv.y)};
    f32x2 a2 = {bf_lo(sv.z), bf_hi(sv.z)};
    f32x2 a3 = {bf_lo(sv.w), bf_hi(sv.w)};

    const int2 se = rowse[n];  // start/end, both multiples of 8
    for (int i = se.x; i < se.y; i += 8) {
        uint4 c = *(const uint4*)&csr[i];  // 8 ushort srcs
        int s0 = c.x & 0xFFFF, s1 = c.x >> 16;
        int s2 = c.y & 0xFFFF, s3 = c.y >> 16;
        int s4 = c.z & 0xFFFF, s5 = c.z >> 16;
        int s6 = c.w & 0xFFFF, s7 = c.w >> 16;
        uint4 v0 = *(const uint4*)&slice[s0 * CHUNK_U + u0];
        uint4 v1 = *(const uint4*)&slice[s1 * CHUNK_U + u0];
        uint4 v2 = *(const uint4*)&slice[s2 * CHUNK_U + u0];
        uint4 v3 = *(const uint4*)&slice[s3 * CHUNK_U + u0];
        uint4 v4 = *(const uint4*)&slice[s4 * CHUNK_U + u0];
        uint4 v5 = *(const uint4*)&slice[s5 * CHUNK_U + u0];
        uint4 v6 = *(const uint4*)&slice[s6 * CHUNK_U + u0];
        uint4 v7 = *(const uint4*)&slice[s7 * CHUNK_U + u0];
        pkadd(a0, v0.x); pkadd(a1, v0.y); pkadd(a2, v0.z); pkadd(a3, v0.w);
        pkadd(a0, v1.x); pkadd(a1, v1.y); pkadd(a2, v1.z); pkadd(a3, v1.w);
        pkadd(a0, v2.x); pkadd(a1, v2.y); pkadd(a2, v2.z); pkadd(a3, v2.w);
        pkadd(a0, v3.x); pkadd(a1, v3.y); pkadd(a2, v3.z); pkadd(a3, v3.w);
        pkadd(a0, v4.x); pkadd(a1, v4.y); pkadd(a2, v4.z); pkadd(a3, v4.w);
        pkadd(a0, v5.x); pkadd(a1, v5.y); pkadd(a2, v5.z); pkadd(a3, v5.w);
        pkadd(a0, v6.x); pkadd(a1, v6.y); pkadd(a2, v6.z); pkadd(a3, v6.w);
        pkadd(a0, v7.x); pkadd(a1, v7.y); pkadd(a2, v7.z); pkadd(a3, v7.w);
    }

    const float d = dinv[n];
    if (MODE == 1) {
        const int gr = batch[n];
        float* __restrict__ pp =
            poolpart + (nb & (NPART - 1)) * (NG * H) + gr * H + chunk * 32 + u0 * 2;
        atomicAdd(&pp[0], a0.x * d);
        atomicAdd(&pp[1], a0.y * d);
        atomicAdd(&pp[2], a1.x * d);
        atomicAdd(&pp[3], a1.y * d);
        atomicAdd(&pp[4], a2.x * d);
        atomicAdd(&pp[5], a2.y * d);
        atomicAdd(&pp[6], a3.x * d);
        atomicAdd(&pp[7], a3.y * d);
        return;
    }
    const float2* bp = (const float2*)bias + chunk * CHUNK_U + u0;
    float2 q0 = bp[0], q1 = bp[1], q2 = bp[2], q3 = bp[3];
    uint4 o;
    o.x = pack_bf16x2(fmaxf(a0.x * d + q0.x, 0.f), fmaxf(a0.y * d + q0.y, 0.f));
    o.y = pack_bf16x2(fmaxf(a1.x * d + q1.x, 0.f), fmaxf(a1.y * d + q1.y, 0.f));
    o.z = pack_bf16x2(fmaxf(a2.x * d + q2.x, 0.f), fmaxf(a2.y * d + q2.y, 0.f));
    o.w = pack_bf16x2(fmaxf(a3.x * d + q3.x, 0.f), fmaxf(a3.y * d + q3.y, 0.f));
    *(uint4*)&outc[(size_t)chunk * (NPAD * CHUNK_U) + (size_t)n * CHUNK_U + u0] = o;
}

// ============ final MLP (single block): reduce NPART copies, +b4, then GEMMs ============
__global__ __launch_bounds__(1024) void mlp_kernel(const float* __restrict__ poolpart,
                                                   const int* __restrict__ pcnt,
                                                   const float* __restrict__ b4,
                                                   const float* __restrict__ lw1,
                                                   const float* __restrict__ lb1,
                                                   const float* __restrict__ lw2,
                                                   const float* __restrict__ lb2,
                                                   float* __restrict__ out) {
    __shared__ float mean_s[NG * H];
    __shared__ float cnt_s[NG];
    __shared__ float hid_s[NG * 64];
    int tid = threadIdx.x;
    if (tid < NG) cnt_s[tid] = fmaxf((float)pcnt[tid], 1.0f);
    __syncthreads();
    for (int i = tid; i < NG * H; i += 1024) {
        float s = 0.f;
        for (int p = 0; p < NPART; p++) s += poolpart[p * (NG * H) + i];
        mean_s[i] = s / cnt_s[i >> 7] + b4[i & (H - 1)];
    }
    __syncthreads();
    {
        int g = tid >> 6, j = tid & 63;
        float acc = lb1[j];
        for (int f = 0; f < H; f++) acc += mean_s[g * H + f] * lw1[f * 64 + j];
        hid_s[g * 64 + j] = fmaxf(acc, 0.f);
    }
    __syncthreads();
    if (tid < 32) {
        int g = tid >> 1, c = tid & 1;
        float acc = lb2[c];
        for (int j = 0; j < 64; j++) acc += hid_s[g * 64 + j] * lw2[j * 2 + c];
        out[g * 2 + c] = acc;
    }
}

extern "C" void kernel_launch(void* const* d_in, const int* in_sizes, int n_in,
                              void* d_out, int out_size, void* d_ws, size_t ws_size,
                              hipStream_t stream) {
    const float* x = (const float*)d_in[0];
    const int* ei = (const int*)d_in[1];
    const int* batch = (const int*)d_in[2];
    const float* W1 = (const float*)d_in[3];
    const float* b1 = (const float*)d_in[4];
    const float* W2 = (const float*)d_in[5];
    const float* b2 = (const float*)d_in[6];
    const float* W3 = (const float*)d_in[7];
    const float* b3 = (const float*)d_in[8];
    const float* W4 = (const float*)d_in[9];
    const float* b4 = (const float*)d_in[10];
    const float* lw1 = (const float*)d_in[11];
    const float* lb1 = (const float*)d_in[12];
    const float* lw2 = (const float*)d_in[13];
    const float* lb2 = (const float*)d_in[14];
    float* out = (float*)d_out;

    // workspace layout (4-byte units; sizes annotated in ints); ~39.8 MB
    int* wsi = (int*)d_ws;
    int* gcount = wsi;                                      // @0        256
    int* galloc = wsi + 256;                                // @256      1
    int* classCnt = wsi + 264;                              // @264      16
    int* pcnt = wsi + 280;                                  // @280      16 (zeroed to 512)
    float* poolpart = (float*)(wsi + 512);                  // @512      131072 (NPART*NG*H)
    int2* rowse = (int2*)(wsi + 131584);                    // @131584   100096 (NPAD int2)
    unsigned short* csr = (unsigned short*)(wsi + 231680);  // @231680   600000 (1.2M ushorts)
    float* dinv = (float*)(wsi + 831680);                   // @831680   50048
    unsigned short* Wt1 = (unsigned short*)(wsi + 881728);  // @881728   4096 (8192 shorts)
    unsigned short* Wt2 = (unsigned short*)(wsi + 885824);  // @885824   8192 (16384 shorts)
    unsigned short* Wt3 = (unsigned short*)(wsi + 894016);  // @894016   8192
    unsigned short* Wt4 = (unsigned short*)(wsi + 902208);  // @902208   8192
    unsigned short* xb = (unsigned short*)(wsi + 910400);   // @910400   1601536 (NPAD*64 shorts)
    unsigned int* hb = (unsigned int*)(wsi + 2511936);      // @2511936  3203072 (NPAD*64 uints)
    unsigned int* hwb = (unsigned int*)(wsi + 5715008);     // @5715008  3203072
    unsigned int* ebuf = (unsigned int*)(wsi + 8918080);    // @8918080  940800
    int* nclass = wsi + 9858880;                            // @9858880  50048
    int* perm = wsi + 9908928;                              // @9908928  50048 -> ends 9958976

    const int gemmBlocks = NPAD / 64;          // 782
    const int aggBlocks = 4 * AGG_CH;          // 3128, chunk-major

    // ---- zero control vars (tiny); pool partials zeroed inside prep ----
    hipMemsetAsync(wsi, 0, 512 * sizeof(int), stream);
    fillA_prep_kernel<<<FILLA_BLOCKS + PREP_BLOCKS, 256, 0, stream>>>(
        ei, gcount, ebuf, x, W1, W2, W3, W4, xb, Wt1, Wt2, Wt3, Wt4, (int4*)poolpart);
    fillB_kernel<<<NBUCK, 256, 0, stream>>>(ebuf, gcount, galloc, classCnt, pcnt, batch,
                                            rowse, dinv, nclass, csr);

    // ---- layer 1 (gemm also builds perm) ----
    gemm_mfma_kernel<FIN, true><<<gemmBlocks, 256, 0, stream>>>(xb, Wt1, dinv, nclass,
                                                                classCnt, perm, hwb);
    agg_kernel<0><<<aggBlocks, 256, 0, stream>>>(hwb, rowse, csr, dinv, b1, perm, batch,
                                                 nullptr, hb);
    // ---- layer 2 ----
    gemm_mfma_kernel<H, false><<<gemmBlocks, 256, 0, stream>>>((unsigned short*)hb, Wt2, dinv,
                                                               nullptr, nullptr, nullptr, hwb);
    agg_kernel<0><<<aggBlocks, 256, 0, stream>>>(hwb, rowse, csr, dinv, b2, perm, batch,
                                                 nullptr, hb);
    // ---- layer 3 ----
    gemm_mfma_kernel<H, false><<<gemmBlocks, 256, 0, stream>>>((unsigned short*)hb, Wt3, dinv,
                                                               nullptr, nullptr, nullptr, hwb);
    agg_kernel<0><<<aggBlocks, 256, 0, stream>>>(hwb, rowse, csr, dinv, b3, perm, batch,
                                                 nullptr, hb);
    // ---- layer 4: agg fused with pooling (b4 applied in mlp) ----
    gemm_mfma_kernel<H, false><<<gemmBlocks, 256, 0, stream>>>((unsigned short*)hb, Wt4, dinv,
                                                               nullptr, nullptr, nullptr, hwb);
    agg_kernel<1><<<aggBlocks, 256, 0, stream>>>(hwb, rowse, csr, dinv, nullptr, perm, batch,
                                                 poolpart, nullptr);

    // ---- final MLP ----
    mlp_kernel<<<1, 1024, 0, stream>>>(poolpart, pcnt, b4, lw1, lb1, lw2, lb2, out);
}

// Round 3
// 560.087 us; speedup vs baseline: 1.1327x; 1.1327x over previous
//
#include <hip/hip_runtime.h>

#define NN 50000
#define NPAD 50048   // rows padded to multiple of 64 for MFMA tiles
#define NE 800000
#define FIN 64
#define H 128
#define NG 16
#define NPART 64         // private pooled-accumulator copies (atomic spreading)
#define NBUCK 196        // buckets of 256 dst nodes
#define BUCK_CAP 4800    // edges per bucket capacity (expected 4096 +- 64)
#define FILLA_BLOCKS 512
#define FILLA_CHUNK 1563  // ceil(NE / FILLA_BLOCKS)
#define CHUNK_U 16       // uints per node per feature-chunk (32 feats)
#define DUMMY NN         // zero pad row used for CSR padding
#define AGG_CH (NPAD / 64) // 782 blocks per chunk (64 nodes/block)
#define ZERO_I4 32768    // int4s to zero: poolpart = 131072 ints
#define PREP_ITEMS (NPAD * FIN + H * FIN + 3 * H * H + ZERO_I4)
#define PREP_BLOCKS ((PREP_ITEMS + 255) / 256)

typedef __bf16 bf16x8 __attribute__((ext_vector_type(8)));
typedef float f32x4 __attribute__((ext_vector_type(4)));
typedef float f32x2 __attribute__((ext_vector_type(2)));

// ---- helpers ----
__device__ inline unsigned short bf16r(float x) {
    unsigned int u = __float_as_uint(x);
    return (unsigned short)((u + 0x7fffu + ((u >> 16) & 1u)) >> 16);
}
__device__ inline unsigned int pack_bf16x2(float a, float b) {
    return (unsigned int)bf16r(a) | ((unsigned int)bf16r(b) << 16);
}
__device__ inline float bf_lo(unsigned int u) { return __uint_as_float(u << 16); }
__device__ inline float bf_hi(unsigned int u) { return __uint_as_float(u & 0xffff0000u); }

// packed fp32 add: acc(pair) += {lo(u), hi(u)}
__device__ inline void pkadd(f32x2& a, unsigned int u) {
    f32x2 p;
    p.x = bf_lo(u);
    p.y = bf_hi(u);
    asm("v_pk_add_f32 %0, %1, %0" : "+v"(a) : "v"(p));
}

// ====== fillA + prep merged: blocks [0,512) bucket edges; rest convert x/W + zero pool ======
__global__ __launch_bounds__(256) void fillA_prep_kernel(const int* __restrict__ ei,
                                                         int* __restrict__ gcount,
                                                         unsigned int* __restrict__ ebuf,
                                                         const float* __restrict__ x,
                                                         const float* __restrict__ W1,
                                                         const float* __restrict__ W2,
                                                         const float* __restrict__ W3,
                                                         const float* __restrict__ W4,
                                                         unsigned short* __restrict__ xb,
                                                         unsigned short* __restrict__ Wt1,
                                                         unsigned short* __restrict__ Wt2,
                                                         unsigned short* __restrict__ Wt3,
                                                         unsigned short* __restrict__ Wt4,
                                                         int4* __restrict__ zbuf) {
    const int t = threadIdx.x;
    if (blockIdx.x >= FILLA_BLOCKS) {
        // ---- prep part ----
        int e = (blockIdx.x - FILLA_BLOCKS) * 256 + t;
        if (e < NPAD * FIN) {
            int n = e >> 6, k = e & 63;
            unsigned short v = (n < NN) ? bf16r(x[n * FIN + k]) : (unsigned short)0;
            xb[(size_t)(k >> 5) * (NPAD * 32) + n * 32 + (k & 31)] = v;
            return;
        }
        int tt = e - NPAD * FIN;
        if (tt < H * FIN) {
            int n = tt / FIN, k = tt % FIN;
            Wt1[tt] = bf16r(W1[k * H + n]);
            return;
        }
        int u = tt - H * FIN;
        if (u < 3 * H * H) {
            const float* W = W2;
            unsigned short* Wt = Wt2;
            if (u >= 2 * H * H) { W = W4; Wt = Wt4; u -= 2 * H * H; }
            else if (u >= H * H) { W = W3; Wt = Wt3; u -= H * H; }
            int n = u / H, k = u % H;
            Wt[u] = bf16r(W[k * H + n]);
            return;
        }
        int z = u - 3 * H * H;
        if (z < ZERO_I4) zbuf[z] = make_int4(0, 0, 0, 0);  // zero pool partials
        return;
    }
    // ---- fillA part: histogram into 196 buckets of 256 nodes ----
    __shared__ int hist[256];
    __shared__ int base[256];
    hist[t] = 0;
    __syncthreads();
    const int e0 = blockIdx.x * FILLA_CHUNK;
    const int e1 = min(e0 + FILLA_CHUNK, NE);
    for (int e = e0 + t; e < e1; e += 256)
        atomicAdd(&hist[ei[NE + e] >> 8], 1);
    __syncthreads();
    {
        int h = hist[t];
        base[t] = h ? atomicAdd(&gcount[t], h) : 0;
    }
    __syncthreads();
    for (int e = e0 + t; e < e1; e += 256) {
        int d = ei[NE + e];
        int s = ei[e];
        int b = d >> 8;
        int pos = atomicAdd(&base[b], 1);
        ebuf[b * BUCK_CAP + pos] = (unsigned int)s | ((unsigned int)d << 16);
    }
}

// fillB (fused hist+scan+scatter), 196 blocks, 1 node per thread.
// Also accumulates per-graph node counts (pcnt) for the pooled mean.
__global__ __launch_bounds__(256) void fillB_kernel(const unsigned int* __restrict__ ebuf,
                                                    const int* __restrict__ gcount,
                                                    int* __restrict__ galloc,
                                                    int* __restrict__ pcnt,
                                                    const int* __restrict__ batch,
                                                    int2* __restrict__ rowse,
                                                    float* __restrict__ dinv,
                                                    unsigned short* __restrict__ csr) {
    __shared__ int lh[256];
    __shared__ int lsum[256];
    __shared__ int lcur[256];
    __shared__ int lgc[16];
    __shared__ int base_s;
    const int b = blockIdx.x, t = threadIdx.x;
    const int n0 = b * 256;
    lh[t] = 0;
    if (t < 16) lgc[t] = 0;
    __syncthreads();
    const int ne = gcount[b];
    const unsigned int* __restrict__ eb = ebuf + b * BUCK_CAP;
    for (int i = t; i < ne; i += 256)
        atomicAdd(&lh[(int)(eb[i] >> 16) - n0], 1);
    __syncthreads();
    const int c = lh[t];
    const int p = (c + 7) & ~7;
    const int n = n0 + t;
    if (n < NN) atomicAdd(&lgc[batch[n]], 1);
    lsum[t] = p;
    __syncthreads();
    if (t < 16 && lgc[t]) atomicAdd(&pcnt[t], lgc[t]);
    for (int off = 1; off < 256; off <<= 1) {
        int u = (t >= off) ? lsum[t - off] : 0;
        __syncthreads();
        lsum[t] += u;
        __syncthreads();
    }
    if (t == 255) base_s = atomicAdd(galloc, lsum[255]);
    const int excl = t ? lsum[t - 1] : 0;
    __syncthreads();
    const int st = base_s + excl;
    if (n < NN) {
        rowse[n] = make_int2(st, st + p);
        dinv[n] = rsqrtf((float)c + 1.0f);  // +1 self-loop
    } else if (n < NPAD) {
        rowse[n] = make_int2(0, 0);
        dinv[n] = 0.0f;
    }
    lcur[t] = st;
    __syncthreads();
    for (int i = t; i < ne; i += 256) {
        unsigned int u = eb[i];
        int pos = atomicAdd(&lcur[(int)(u >> 16) - n0], 1);
        csr[pos] = (unsigned short)(u & 0xFFFFu);
    }
    __syncthreads();
    for (int k = st + c; k < st + p; k++) csr[k] = (unsigned short)DUMMY;
}

// ===== MFMA GEMM (chunked in/out): hw' = (h @ W) * dinv[row], bf16 out =====
#define LSTRIDE 130
template <int K>
__global__ __launch_bounds__(256) void gemm_mfma_kernel(const unsigned short* __restrict__ hb,
                                                        const unsigned short* __restrict__ Wt,
                                                        const float* __restrict__ dinv,
                                                        unsigned int* __restrict__ outu) {
    __shared__ float ls[64 * LSTRIDE];  // ~33 KB
    const int wave = threadIdx.x >> 6, lane = threadIdx.x & 63;
    const int m15 = lane & 15, quad = lane >> 4;
    const int row0 = blockIdx.x * 64;
    const int arow = row0 + wave * 16 + m15;

    bf16x8 a[K / 32];
#pragma unroll
    for (int ks = 0; ks < K / 32; ks++)
        a[ks] = *(const bf16x8*)&hb[(size_t)ks * (NPAD * 32) + arow * 32 + quad * 8];

    const int lrow = wave * 16 + quad * 4;
    float dv[4];
#pragma unroll
    for (int r = 0; r < 4; r++) dv[r] = dinv[row0 + lrow + r];

#pragma unroll
    for (int ct = 0; ct < 8; ct++) {
        f32x4 acc = {0.f, 0.f, 0.f, 0.f};
#pragma unroll
        for (int ks = 0; ks < K / 32; ks++) {
            bf16x8 b = *(const bf16x8*)&Wt[(ct * 16 + m15) * K + ks * 32 + quad * 8];
            acc = __builtin_amdgcn_mfma_f32_16x16x32_bf16(a[ks], b, acc, 0, 0, 0);
        }
#pragma unroll
        for (int r = 0; r < 4; r++)
            ls[(lrow + r) * LSTRIDE + ct * 16 + m15] = acc[r] * dv[r];
    }
    __syncthreads();

#pragma unroll
    for (int k = 0; k < 4; k++) {
        int idx = threadIdx.x + 256 * k;
        int c = idx >> 8, row = (idx >> 2) & 63, q = idx & 3;
        const float* p = &ls[row * LSTRIDE + c * 32 + q * 8];
        uint4 o;
        o.x = pack_bf16x2(p[0], p[1]);
        o.y = pack_bf16x2(p[2], p[3]);
        o.z = pack_bf16x2(p[4], p[5]);
        o.w = pack_bf16x2(p[6], p[7]);
        *(uint4*)&outu[(size_t)c * (NPAD * CHUNK_U) + (size_t)(row0 + row) * CHUNK_U + q * 4] = o;
    }
}

// ====== feature-chunked gather aggregation, sequential node order ======
// 4 lanes per node, uint4 gathers, v_pk_add_f32 accumulation.
// MODE 0: relu(x*dinv + bias) -> bf16 store.   MODE 1: pool atomics (layer 4).
template <int MODE>
__global__ __launch_bounds__(256) void agg_kernel(const unsigned int* __restrict__ hwc,
                                                  const int2* __restrict__ rowse,
                                                  const unsigned short* __restrict__ csr,
                                                  const float* __restrict__ dinv,
                                                  const float* __restrict__ bias,
                                                  const int* __restrict__ batch,
                                                  float* __restrict__ poolpart,
                                                  unsigned int* __restrict__ outc) {
    const int chunk = blockIdx.x / AGG_CH;
    const int nb = blockIdx.x % AGG_CH;
    const int g = threadIdx.x & 3;               // lane's uint-quad within the chunk
    const int n = nb * 64 + (threadIdx.x >> 2);  // node (64 per block, incl. pad rows)
    if (MODE == 1 && n >= NN) return;            // pads contribute nothing to pooling
    const int u0 = g * 4;
    const unsigned int* __restrict__ slice = hwc + (size_t)chunk * (NPAD * CHUNK_U);

    uint4 sv = *(const uint4*)&slice[n * CHUNK_U + u0];  // self-loop term
    f32x2 a0 = {bf_lo(sv.x), bf_hi(sv.x)};
    f32x2 a1 = {bf_lo(sv.y), bf_hi(sv.y)};
    f32x2 a2 = {bf_lo(sv.z), bf_hi(sv.z)};
    f32x2 a3 = {bf_lo(sv.w), bf_hi(sv.w)};

    const int2 se = rowse[n];  // start/end, both multiples of 8
    for (int i = se.x; i < se.y; i += 8) {
        uint4 c = *(const uint4*)&csr[i];  // 8 ushort srcs
        int s0 = c.x & 0xFFFF, s1 = c.x >> 16;
        int s2 = c.y & 0xFFFF, s3 = c.y >> 16;
        int s4 = c.z & 0xFFFF, s5 = c.z >> 16;
        int s6 = c.w & 0xFFFF, s7 = c.w >> 16;
        uint4 v0 = *(const uint4*)&slice[s0 * CHUNK_U + u0];
        uint4 v1 = *(const uint4*)&slice[s1 * CHUNK_U + u0];
        uint4 v2 = *(const uint4*)&slice[s2 * CHUNK_U + u0];
        uint4 v3 = *(const uint4*)&slice[s3 * CHUNK_U + u0];
        uint4 v4 = *(const uint4*)&slice[s4 * CHUNK_U + u0];
        uint4 v5 = *(const uint4*)&slice[s5 * CHUNK_U + u0];
        uint4 v6 = *(const uint4*)&slice[s6 * CHUNK_U + u0];
        uint4 v7 = *(const uint4*)&slice[s7 * CHUNK_U + u0];
        pkadd(a0, v0.x); pkadd(a1, v0.y); pkadd(a2, v0.z); pkadd(a3, v0.w);
        pkadd(a0, v1.x); pkadd(a1, v1.y); pkadd(a2, v1.z); pkadd(a3, v1.w);
        pkadd(a0, v2.x); pkadd(a1, v2.y); pkadd(a2, v2.z); pkadd(a3, v2.w);
        pkadd(a0, v3.x); pkadd(a1, v3.y); pkadd(a2, v3.z); pkadd(a3, v3.w);
        pkadd(a0, v4.x); pkadd(a1, v4.y); pkadd(a2, v4.z); pkadd(a3, v4.w);
        pkadd(a0, v5.x); pkadd(a1, v5.y); pkadd(a2, v5.z); pkadd(a3, v5.w);
        pkadd(a0, v6.x); pkadd(a1, v6.y); pkadd(a2, v6.z); pkadd(a3, v6.w);
        pkadd(a0, v7.x); pkadd(a1, v7.y); pkadd(a2, v7.z); pkadd(a3, v7.w);
    }

    const float d = dinv[n];
    if (MODE == 1) {
        const int gr = batch[n];
        float* __restrict__ pp =
            poolpart + (nb & (NPART - 1)) * (NG * H) + gr * H + chunk * 32 + u0 * 2;
        atomicAdd(&pp[0], a0.x * d);
        atomicAdd(&pp[1], a0.y * d);
        atomicAdd(&pp[2], a1.x * d);
        atomicAdd(&pp[3], a1.y * d);
        atomicAdd(&pp[4], a2.x * d);
        atomicAdd(&pp[5], a2.y * d);
        atomicAdd(&pp[6], a3.x * d);
        atomicAdd(&pp[7], a3.y * d);
        return;
    }
    const float2* bp = (const float2*)bias + chunk * CHUNK_U + u0;
    float2 q0 = bp[0], q1 = bp[1], q2 = bp[2], q3 = bp[3];
    uint4 o;
    o.x = pack_bf16x2(fmaxf(a0.x * d + q0.x, 0.f), fmaxf(a0.y * d + q0.y, 0.f));
    o.y = pack_bf16x2(fmaxf(a1.x * d + q1.x, 0.f), fmaxf(a1.y * d + q1.y, 0.f));
    o.z = pack_bf16x2(fmaxf(a2.x * d + q2.x, 0.f), fmaxf(a2.y * d + q2.y, 0.f));
    o.w = pack_bf16x2(fmaxf(a3.x * d + q3.x, 0.f), fmaxf(a3.y * d + q3.y, 0.f));
    *(uint4*)&outc[(size_t)chunk * (NPAD * CHUNK_U) + (size_t)n * CHUNK_U + u0] = o;
}

// ============ final MLP (single block): reduce NPART copies, +b4, then GEMMs ============
__global__ __launch_bounds__(1024) void mlp_kernel(const float* __restrict__ poolpart,
                                                   const int* __restrict__ pcnt,
                                                   const float* __restrict__ b4,
                                                   const float* __restrict__ lw1,
                                                   const float* __restrict__ lb1,
                                                   const float* __restrict__ lw2,
                                                   const float* __restrict__ lb2,
                                                   float* __restrict__ out) {
    __shared__ float mean_s[NG * H];
    __shared__ float cnt_s[NG];
    __shared__ float hid_s[NG * 64];
    int tid = threadIdx.x;
    if (tid < NG) cnt_s[tid] = fmaxf((float)pcnt[tid], 1.0f);
    __syncthreads();
    for (int i = tid; i < NG * H; i += 1024) {
        float s = 0.f;
        for (int p = 0; p < NPART; p++) s += poolpart[p * (NG * H) + i];
        mean_s[i] = s / cnt_s[i >> 7] + b4[i & (H - 1)];
    }
    __syncthreads();
    {
        int g = tid >> 6, j = tid & 63;
        float acc = lb1[j];
        for (int f = 0; f < H; f++) acc += mean_s[g * H + f] * lw1[f * 64 + j];
        hid_s[g * 64 + j] = fmaxf(acc, 0.f);
    }
    __syncthreads();
    if (tid < 32) {
        int g = tid >> 1, c = tid & 1;
        float acc = lb2[c];
        for (int j = 0; j < 64; j++) acc += hid_s[g * 64 + j] * lw2[j * 2 + c];
        out[g * 2 + c] = acc;
    }
}

extern "C" void kernel_launch(void* const* d_in, const int* in_sizes, int n_in,
                              void* d_out, int out_size, void* d_ws, size_t ws_size,
                              hipStream_t stream) {
    const float* x = (const float*)d_in[0];
    const int* ei = (const int*)d_in[1];
    const int* batch = (const int*)d_in[2];
    const float* W1 = (const float*)d_in[3];
    const float* b1 = (const float*)d_in[4];
    const float* W2 = (const float*)d_in[5];
    const float* b2 = (const float*)d_in[6];
    const float* W3 = (const float*)d_in[7];
    const float* b3 = (const float*)d_in[8];
    const float* W4 = (const float*)d_in[9];
    const float* b4 = (const float*)d_in[10];
    const float* lw1 = (const float*)d_in[11];
    const float* lb1 = (const float*)d_in[12];
    const float* lw2 = (const float*)d_in[13];
    const float* lb2 = (const float*)d_in[14];
    float* out = (float*)d_out;

    // workspace layout (4-byte units; sizes annotated in ints); ~39.5 MB
    int* wsi = (int*)d_ws;
    int* gcount = wsi;                                      // @0        256
    int* galloc = wsi + 256;                                // @256      1
    int* pcnt = wsi + 280;                                  // @280      16 (zeroed to 512)
    float* poolpart = (float*)(wsi + 512);                  // @512      131072 (NPART*NG*H)
    int2* rowse = (int2*)(wsi + 131584);                    // @131584   100096 (NPAD int2)
    unsigned short* csr = (unsigned short*)(wsi + 231680);  // @231680   600000 (1.2M ushorts)
    float* dinv = (float*)(wsi + 831680);                   // @831680   50048
    unsigned short* Wt1 = (unsigned short*)(wsi + 881728);  // @881728   4096 (8192 shorts)
    unsigned short* Wt2 = (unsigned short*)(wsi + 885824);  // @885824   8192 (16384 shorts)
    unsigned short* Wt3 = (unsigned short*)(wsi + 894016);  // @894016   8192
    unsigned short* Wt4 = (unsigned short*)(wsi + 902208);  // @902208   8192
    unsigned short* xb = (unsigned short*)(wsi + 910400);   // @910400   1601536 (NPAD*64 shorts)
    unsigned int* hb = (unsigned int*)(wsi + 2511936);      // @2511936  3203072 (NPAD*64 uints)
    unsigned int* hwb = (unsigned int*)(wsi + 5715008);     // @5715008  3203072
    unsigned int* ebuf = (unsigned int*)(wsi + 8918080);    // @8918080  940800 -> ends 9858880

    const int gemmBlocks = NPAD / 64;          // 782
    const int aggBlocks = 4 * AGG_CH;          // 3128, chunk-major

    // ---- zero control vars (tiny); pool partials zeroed inside prep ----
    hipMemsetAsync(wsi, 0, 512 * sizeof(int), stream);
    fillA_prep_kernel<<<FILLA_BLOCKS + PREP_BLOCKS, 256, 0, stream>>>(
        ei, gcount, ebuf, x, W1, W2, W3, W4, xb, Wt1, Wt2, Wt3, Wt4, (int4*)poolpart);
    fillB_kernel<<<NBUCK, 256, 0, stream>>>(ebuf, gcount, galloc, pcnt, batch,
                                            rowse, dinv, csr);

    // ---- layer 1 ----
    gemm_mfma_kernel<FIN><<<gemmBlocks, 256, 0, stream>>>(xb, Wt1, dinv, hwb);
    agg_kernel<0><<<aggBlocks, 256, 0, stream>>>(hwb, rowse, csr, dinv, b1, batch,
                                                 nullptr, hb);
    // ---- layer 2 ----
    gemm_mfma_kernel<H><<<gemmBlocks, 256, 0, stream>>>((unsigned short*)hb, Wt2, dinv, hwb);
    agg_kernel<0><<<aggBlocks, 256, 0, stream>>>(hwb, rowse, csr, dinv, b2, batch,
                                                 nullptr, hb);
    // ---- layer 3 ----
    gemm_mfma_kernel<H><<<gemmBlocks, 256, 0, stream>>>((unsigned short*)hb, Wt3, dinv, hwb);
    agg_kernel<0><<<aggBlocks, 256, 0, stream>>>(hwb, rowse, csr, dinv, b3, batch,
                                                 nullptr, hb);
    // ---- layer 4: agg fused with pooling (b4 applied in mlp) ----
    gemm_mfma_kernel<H><<<gemmBlocks, 256, 0, stream>>>((unsigned short*)hb, Wt4, dinv, hwb);
    agg_kernel<1><<<aggBlocks, 256, 0, stream>>>(hwb, rowse, csr, dinv, nullptr, batch,
                                                 poolpart, nullptr);

    // ---- final MLP ----
    mlp_kernel<<<1, 1024, 0, stream>>>(poolpart, pcnt, b4, lw1, lb1, lw2, lb2, out);
}

// Round 4
// 346.609 us; speedup vs baseline: 1.8303x; 1.6159x over previous
//
#include <hip/hip_runtime.h>

#define NN 50000
#define NPAD 50048   // rows padded to multiple of 64 for MFMA tiles
#define NE 800000
#define FIN 64
#define H 128
#define NG 16
#define NPART 64         // private pooled-accumulator copies (atomic spreading)
#define NBUCK 196        // buckets of 256 dst nodes
#define BUCK_CAP 4800    // edges per bucket capacity (expected 4096 +- 64)
#define FILLA_BLOCKS 512
#define FILLA_CHUNK 1563  // ceil(NE / FILLA_BLOCKS)
#define CHUNK_U 16       // uints per node per feature-chunk (32 feats)
#define DUMMY NN         // zero pad row used for CSR padding
#define AGG_CH (NPAD / 64) // 782 blocks per chunk (64 nodes/block)
#define ZERO_I4 32768    // int4s to zero: poolpart = 131072 ints
#define PREP_ITEMS (NPAD * FIN + H * FIN + 3 * H * H + ZERO_I4)
#define PREP_BLOCKS ((PREP_ITEMS + 255) / 256)

typedef __bf16 bf16x8 __attribute__((ext_vector_type(8)));
typedef float f32x4 __attribute__((ext_vector_type(4)));
typedef float f32x2 __attribute__((ext_vector_type(2)));

// ---- helpers ----
__device__ inline unsigned short bf16r(float x) {
    unsigned int u = __float_as_uint(x);
    return (unsigned short)((u + 0x7fffu + ((u >> 16) & 1u)) >> 16);
}
__device__ inline unsigned int pack_bf16x2(float a, float b) {
    return (unsigned int)bf16r(a) | ((unsigned int)bf16r(b) << 16);
}
__device__ inline float bf_lo(unsigned int u) { return __uint_as_float(u << 16); }
__device__ inline float bf_hi(unsigned int u) { return __uint_as_float(u & 0xffff0000u); }

// packed fp32 add: acc(pair) += {lo(u), hi(u)}
__device__ inline void pkadd(f32x2& a, unsigned int u) {
    f32x2 p;
    p.x = bf_lo(u);
    p.y = bf_hi(u);
    asm("v_pk_add_f32 %0, %1, %0" : "+v"(a) : "v"(p));
}

// ====== fillA + prep merged: blocks [0,512) bucket edges; rest convert x/W + zero pool ======
__global__ __launch_bounds__(256) void fillA_prep_kernel(const int* __restrict__ ei,
                                                         int* __restrict__ gcount,
                                                         unsigned int* __restrict__ ebuf,
                                                         const float* __restrict__ x,
                                                         const float* __restrict__ W1,
                                                         const float* __restrict__ W2,
                                                         const float* __restrict__ W3,
                                                         const float* __restrict__ W4,
                                                         unsigned short* __restrict__ xb,
                                                         unsigned short* __restrict__ Wt1,
                                                         unsigned short* __restrict__ Wt2,
                                                         unsigned short* __restrict__ Wt3,
                                                         unsigned short* __restrict__ Wt4,
                                                         int4* __restrict__ zbuf) {
    const int t = threadIdx.x;
    if (blockIdx.x >= FILLA_BLOCKS) {
        // ---- prep part ----
        int e = (blockIdx.x - FILLA_BLOCKS) * 256 + t;
        if (e < NPAD * FIN) {
            int n = e >> 6, k = e & 63;
            unsigned short v = (n < NN) ? bf16r(x[n * FIN + k]) : (unsigned short)0;
            xb[(size_t)(k >> 5) * (NPAD * 32) + n * 32 + (k & 31)] = v;
            return;
        }
        int tt = e - NPAD * FIN;
        if (tt < H * FIN) {
            int n = tt / FIN, k = tt % FIN;
            Wt1[tt] = bf16r(W1[k * H + n]);
            return;
        }
        int u = tt - H * FIN;
        if (u < 3 * H * H) {
            const float* W = W2;
            unsigned short* Wt = Wt2;
            if (u >= 2 * H * H) { W = W4; Wt = Wt4; u -= 2 * H * H; }
            else if (u >= H * H) { W = W3; Wt = Wt3; u -= H * H; }
            int n = u / H, k = u % H;
            Wt[u] = bf16r(W[k * H + n]);
            return;
        }
        int z = u - 3 * H * H;
        if (z < ZERO_I4) zbuf[z] = make_int4(0, 0, 0, 0);  // zero pool partials
        return;
    }
    // ---- fillA part: histogram into 196 buckets of 256 nodes ----
    __shared__ int hist[256];
    __shared__ int base[256];
    hist[t] = 0;
    __syncthreads();
    const int e0 = blockIdx.x * FILLA_CHUNK;
    const int e1 = min(e0 + FILLA_CHUNK, NE);
    for (int e = e0 + t; e < e1; e += 256)
        atomicAdd(&hist[ei[NE + e] >> 8], 1);
    __syncthreads();
    {
        int h = hist[t];
        base[t] = h ? atomicAdd(&gcount[t], h) : 0;
    }
    __syncthreads();
    for (int e = e0 + t; e < e1; e += 256) {
        int d = ei[NE + e];
        int s = ei[e];
        int b = d >> 8;
        int pos = atomicAdd(&base[b], 1);
        ebuf[b * BUCK_CAP + pos] = (unsigned int)s | ((unsigned int)d << 16);
    }
}

// fillB (fused hist+scan+scatter), 196 blocks, 1 node per thread.
// Also accumulates per-graph node counts (pcnt) for the pooled mean.
__global__ __launch_bounds__(256) void fillB_kernel(const unsigned int* __restrict__ ebuf,
                                                    const int* __restrict__ gcount,
                                                    int* __restrict__ galloc,
                                                    int* __restrict__ pcnt,
                                                    const int* __restrict__ batch,
                                                    int2* __restrict__ rowse,
                                                    float* __restrict__ dinv,
                                                    unsigned short* __restrict__ csr) {
    __shared__ int lh[256];
    __shared__ int lsum[256];
    __shared__ int lcur[256];
    __shared__ int lgc[16];
    __shared__ int base_s;
    const int b = blockIdx.x, t = threadIdx.x;
    const int n0 = b * 256;
    lh[t] = 0;
    if (t < 16) lgc[t] = 0;
    __syncthreads();
    const int ne = gcount[b];
    const unsigned int* __restrict__ eb = ebuf + b * BUCK_CAP;
    for (int i = t; i < ne; i += 256)
        atomicAdd(&lh[(int)(eb[i] >> 16) - n0], 1);
    __syncthreads();
    const int c = lh[t];
    const int p = (c + 7) & ~7;
    const int n = n0 + t;
    if (n < NN) atomicAdd(&lgc[batch[n]], 1);
    lsum[t] = p;
    __syncthreads();
    if (t < 16 && lgc[t]) atomicAdd(&pcnt[t], lgc[t]);
    for (int off = 1; off < 256; off <<= 1) {
        int u = (t >= off) ? lsum[t - off] : 0;
        __syncthreads();
        lsum[t] += u;
        __syncthreads();
    }
    if (t == 255) base_s = atomicAdd(galloc, lsum[255]);
    const int excl = t ? lsum[t - 1] : 0;
    __syncthreads();
    const int st = base_s + excl;
    if (n < NN) {
        rowse[n] = make_int2(st, st + p);
        dinv[n] = rsqrtf((float)c + 1.0f);  // +1 self-loop
    } else if (n < NPAD) {
        rowse[n] = make_int2(0, 0);
        dinv[n] = 0.0f;
    }
    lcur[t] = st;
    __syncthreads();
    for (int i = t; i < ne; i += 256) {
        unsigned int u = eb[i];
        int pos = atomicAdd(&lcur[(int)(u >> 16) - n0], 1);
        csr[pos] = (unsigned short)(u & 0xFFFFu);
    }
    __syncthreads();
    for (int k = st + c; k < st + p; k++) csr[k] = (unsigned short)DUMMY;
}

// ===== MFMA GEMM (chunked in/out): hw' = (h @ W) * dinv[row], bf16 out =====
#define LSTRIDE 130
template <int K>
__global__ __launch_bounds__(256) void gemm_mfma_kernel(const unsigned short* __restrict__ hb,
                                                        const unsigned short* __restrict__ Wt,
                                                        const float* __restrict__ dinv,
                                                        unsigned int* __restrict__ outu) {
    __shared__ float ls[64 * LSTRIDE];  // ~33 KB
    const int wave = threadIdx.x >> 6, lane = threadIdx.x & 63;
    const int m15 = lane & 15, quad = lane >> 4;
    const int row0 = blockIdx.x * 64;
    const int arow = row0 + wave * 16 + m15;

    bf16x8 a[K / 32];
#pragma unroll
    for (int ks = 0; ks < K / 32; ks++)
        a[ks] = *(const bf16x8*)&hb[(size_t)ks * (NPAD * 32) + arow * 32 + quad * 8];

    const int lrow = wave * 16 + quad * 4;
    float dv[4];
#pragma unroll
    for (int r = 0; r < 4; r++) dv[r] = dinv[row0 + lrow + r];

#pragma unroll
    for (int ct = 0; ct < 8; ct++) {
        f32x4 acc = {0.f, 0.f, 0.f, 0.f};
#pragma unroll
        for (int ks = 0; ks < K / 32; ks++) {
            bf16x8 b = *(const bf16x8*)&Wt[(ct * 16 + m15) * K + ks * 32 + quad * 8];
            acc = __builtin_amdgcn_mfma_f32_16x16x32_bf16(a[ks], b, acc, 0, 0, 0);
        }
#pragma unroll
        for (int r = 0; r < 4; r++)
            ls[(lrow + r) * LSTRIDE + ct * 16 + m15] = acc[r] * dv[r];
    }
    __syncthreads();

#pragma unroll
    for (int k = 0; k < 4; k++) {
        int idx = threadIdx.x + 256 * k;
        int c = idx >> 8, row = (idx >> 2) & 63, q = idx & 3;
        const float* p = &ls[row * LSTRIDE + c * 32 + q * 8];
        uint4 o;
        o.x = pack_bf16x2(p[0], p[1]);
        o.y = pack_bf16x2(p[2], p[3]);
        o.z = pack_bf16x2(p[4], p[5]);
        o.w = pack_bf16x2(p[6], p[7]);
        *(uint4*)&outu[(size_t)c * (NPAD * CHUNK_U) + (size_t)(row0 + row) * CHUNK_U + q * 4] = o;
    }
}

// ====== feature-chunked gather aggregation, sequential node order ======
// 4 lanes per node, uint4 gathers, v_pk_add_f32 accumulation.
// MODE 0: relu(x*dinv + bias) -> bf16 store.
// MODE 1 (layer 4): LDS-reduced pooling -> ~32 global atomics per block
//   (NOT per-feature global atomics: 6.4M atomics x 32B = 200 MB HBM RMW storm).
template <int MODE>
__global__ __launch_bounds__(256) void agg_kernel(const unsigned int* __restrict__ hwc,
                                                  const int2* __restrict__ rowse,
                                                  const unsigned short* __restrict__ csr,
                                                  const float* __restrict__ dinv,
                                                  const float* __restrict__ bias,
                                                  const int* __restrict__ batch,
                                                  float* __restrict__ poolpart,
                                                  unsigned int* __restrict__ outc) {
    __shared__ float pool_s[MODE == 1 ? NG * 32 : 1];
    __shared__ int grange_s[2];
    const int chunk = blockIdx.x / AGG_CH;
    const int nb = blockIdx.x % AGG_CH;
    const int g = threadIdx.x & 3;               // lane's uint-quad within the chunk
    const int n = nb * 64 + (threadIdx.x >> 2);  // node (64 per block, incl. pad rows)
    const int u0 = g * 4;
    const unsigned int* __restrict__ slice = hwc + (size_t)chunk * (NPAD * CHUNK_U);

    if (MODE == 1) {
        for (int i = threadIdx.x; i < NG * 32; i += 256) pool_s[i] = 0.f;
        if (threadIdx.x == 0) {
            int nlo = nb * 64;
            grange_s[0] = (nlo < NN) ? batch[nlo] : 0;
            grange_s[1] = (nlo < NN) ? batch[min(nlo + 63, NN - 1)] : -1;
        }
        __syncthreads();
    }

    uint4 sv = *(const uint4*)&slice[n * CHUNK_U + u0];  // self-loop term
    f32x2 a0 = {bf_lo(sv.x), bf_hi(sv.x)};
    f32x2 a1 = {bf_lo(sv.y), bf_hi(sv.y)};
    f32x2 a2 = {bf_lo(sv.z), bf_hi(sv.z)};
    f32x2 a3 = {bf_lo(sv.w), bf_hi(sv.w)};

    const int2 se = rowse[n];  // start/end, both multiples of 8
    for (int i = se.x; i < se.y; i += 8) {
        uint4 c = *(const uint4*)&csr[i];  // 8 ushort srcs
        int s0 = c.x & 0xFFFF, s1 = c.x >> 16;
        int s2 = c.y & 0xFFFF, s3 = c.y >> 16;
        int s4 = c.z & 0xFFFF, s5 = c.z >> 16;
        int s6 = c.w & 0xFFFF, s7 = c.w >> 16;
        uint4 v0 = *(const uint4*)&slice[s0 * CHUNK_U + u0];
        uint4 v1 = *(const uint4*)&slice[s1 * CHUNK_U + u0];
        uint4 v2 = *(const uint4*)&slice[s2 * CHUNK_U + u0];
        uint4 v3 = *(const uint4*)&slice[s3 * CHUNK_U + u0];
        uint4 v4 = *(const uint4*)&slice[s4 * CHUNK_U + u0];
        uint4 v5 = *(const uint4*)&slice[s5 * CHUNK_U + u0];
        uint4 v6 = *(const uint4*)&slice[s6 * CHUNK_U + u0];
        uint4 v7 = *(const uint4*)&slice[s7 * CHUNK_U + u0];
        pkadd(a0, v0.x); pkadd(a1, v0.y); pkadd(a2, v0.z); pkadd(a3, v0.w);
        pkadd(a0, v1.x); pkadd(a1, v1.y); pkadd(a2, v1.z); pkadd(a3, v1.w);
        pkadd(a0, v2.x); pkadd(a1, v2.y); pkadd(a2, v2.z); pkadd(a3, v2.w);
        pkadd(a0, v3.x); pkadd(a1, v3.y); pkadd(a2, v3.z); pkadd(a3, v3.w);
        pkadd(a0, v4.x); pkadd(a1, v4.y); pkadd(a2, v4.z); pkadd(a3, v4.w);
        pkadd(a0, v5.x); pkadd(a1, v5.y); pkadd(a2, v5.z); pkadd(a3, v5.w);
        pkadd(a0, v6.x); pkadd(a1, v6.y); pkadd(a2, v6.z); pkadd(a3, v6.w);
        pkadd(a0, v7.x); pkadd(a1, v7.y); pkadd(a2, v7.z); pkadd(a3, v7.w);
    }

    const float d = dinv[n];
    if (MODE == 1) {
        if (n < NN) {
            // pad rows have d==0 anyway; guard avoids OOB batch[] read
            const int gr = batch[n];
            float* __restrict__ ps = &pool_s[gr * 32 + u0 * 2];
            atomicAdd(&ps[0], a0.x * d);
            atomicAdd(&ps[1], a0.y * d);
            atomicAdd(&ps[2], a1.x * d);
            atomicAdd(&ps[3], a1.y * d);
            atomicAdd(&ps[4], a2.x * d);
            atomicAdd(&ps[5], a2.y * d);
            atomicAdd(&ps[6], a3.x * d);
            atomicAdd(&ps[7], a3.y * d);
        }
        __syncthreads();
        // flush only the (usually 1, sometimes 2) graph ids present in this block
        float* __restrict__ pp = poolpart + (nb & (NPART - 1)) * (NG * H) + chunk * 32;
        for (int gr = grange_s[0]; gr <= grange_s[1]; gr++) {
            if (threadIdx.x < 32) {
                float v = pool_s[gr * 32 + threadIdx.x];
                if (v != 0.f) atomicAdd(&pp[gr * H + threadIdx.x], v);
            }
        }
        return;
    }
    const float2* bp = (const float2*)bias + chunk * CHUNK_U + u0;
    float2 q0 = bp[0], q1 = bp[1], q2 = bp[2], q3 = bp[3];
    uint4 o;
    o.x = pack_bf16x2(fmaxf(a0.x * d + q0.x, 0.f), fmaxf(a0.y * d + q0.y, 0.f));
    o.y = pack_bf16x2(fmaxf(a1.x * d + q1.x, 0.f), fmaxf(a1.y * d + q1.y, 0.f));
    o.z = pack_bf16x2(fmaxf(a2.x * d + q2.x, 0.f), fmaxf(a2.y * d + q2.y, 0.f));
    o.w = pack_bf16x2(fmaxf(a3.x * d + q3.x, 0.f), fmaxf(a3.y * d + q3.y, 0.f));
    *(uint4*)&outc[(size_t)chunk * (NPAD * CHUNK_U) + (size_t)n * CHUNK_U + u0] = o;
}

// ============ final MLP (single block): reduce NPART copies, +b4, then GEMMs ============
__global__ __launch_bounds__(1024) void mlp_kernel(const float* __restrict__ poolpart,
                                                   const int* __restrict__ pcnt,
                                                   const float* __restrict__ b4,
                                                   const float* __restrict__ lw1,
                                                   const float* __restrict__ lb1,
                                                   const float* __restrict__ lw2,
                                                   const float* __restrict__ lb2,
                                                   float* __restrict__ out) {
    __shared__ float mean_s[NG * H];
    __shared__ float cnt_s[NG];
    __shared__ float hid_s[NG * 64];
    int tid = threadIdx.x;
    if (tid < NG) cnt_s[tid] = fmaxf((float)pcnt[tid], 1.0f);
    __syncthreads();
    for (int i = tid; i < NG * H; i += 1024) {
        float s = 0.f;
        for (int p = 0; p < NPART; p++) s += poolpart[p * (NG * H) + i];
        mean_s[i] = s / cnt_s[i >> 7] + b4[i & (H - 1)];
    }
    __syncthreads();
    {
        int g = tid >> 6, j = tid & 63;
        float acc = lb1[j];
        for (int f = 0; f < H; f++) acc += mean_s[g * H + f] * lw1[f * 64 + j];
        hid_s[g * 64 + j] = fmaxf(acc, 0.f);
    }
    __syncthreads();
    if (tid < 32) {
        int g = tid >> 1, c = tid & 1;
        float acc = lb2[c];
        for (int j = 0; j < 64; j++) acc += hid_s[g * 64 + j] * lw2[j * 2 + c];
        out[g * 2 + c] = acc;
    }
}

extern "C" void kernel_launch(void* const* d_in, const int* in_sizes, int n_in,
                              void* d_out, int out_size, void* d_ws, size_t ws_size,
                              hipStream_t stream) {
    const float* x = (const float*)d_in[0];
    const int* ei = (const int*)d_in[1];
    const int* batch = (const int*)d_in[2];
    const float* W1 = (const float*)d_in[3];
    const float* b1 = (const float*)d_in[4];
    const float* W2 = (const float*)d_in[5];
    const float* b2 = (const float*)d_in[6];
    const float* W3 = (const float*)d_in[7];
    const float* b3 = (const float*)d_in[8];
    const float* W4 = (const float*)d_in[9];
    const float* b4 = (const float*)d_in[10];
    const float* lw1 = (const float*)d_in[11];
    const float* lb1 = (const float*)d_in[12];
    const float* lw2 = (const float*)d_in[13];
    const float* lb2 = (const float*)d_in[14];
    float* out = (float*)d_out;

    // workspace layout (4-byte units; sizes annotated in ints); ~39.5 MB
    int* wsi = (int*)d_ws;
    int* gcount = wsi;                                      // @0        256
    int* galloc = wsi + 256;                                // @256      1
    int* pcnt = wsi + 280;                                  // @280      16 (zeroed to 512)
    float* poolpart = (float*)(wsi + 512);                  // @512      131072 (NPART*NG*H)
    int2* rowse = (int2*)(wsi + 131584);                    // @131584   100096 (NPAD int2)
    unsigned short* csr = (unsigned short*)(wsi + 231680);  // @231680   600000 (1.2M ushorts)
    float* dinv = (float*)(wsi + 831680);                   // @831680   50048
    unsigned short* Wt1 = (unsigned short*)(wsi + 881728);  // @881728   4096 (8192 shorts)
    unsigned short* Wt2 = (unsigned short*)(wsi + 885824);  // @885824   8192 (16384 shorts)
    unsigned short* Wt3 = (unsigned short*)(wsi + 894016);  // @894016   8192
    unsigned short* Wt4 = (unsigned short*)(wsi + 902208);  // @902208   8192
    unsigned short* xb = (unsigned short*)(wsi + 910400);   // @910400   1601536 (NPAD*64 shorts)
    unsigned int* hb = (unsigned int*)(wsi + 2511936);      // @2511936  3203072 (NPAD*64 uints)
    unsigned int* hwb = (unsigned int*)(wsi + 5715008);     // @5715008  3203072
    unsigned int* ebuf = (unsigned int*)(wsi + 8918080);    // @8918080  940800 -> ends 9858880

    const int gemmBlocks = NPAD / 64;          // 782
    const int aggBlocks = 4 * AGG_CH;          // 3128, chunk-major

    // ---- zero control vars (tiny); pool partials zeroed inside prep ----
    hipMemsetAsync(wsi, 0, 512 * sizeof(int), stream);
    fillA_prep_kernel<<<FILLA_BLOCKS + PREP_BLOCKS, 256, 0, stream>>>(
        ei, gcount, ebuf, x, W1, W2, W3, W4, xb, Wt1, Wt2, Wt3, Wt4, (int4*)poolpart);
    fillB_kernel<<<NBUCK, 256, 0, stream>>>(ebuf, gcount, galloc, pcnt, batch,
                                            rowse, dinv, csr);

    // ---- layer 1 ----
    gemm_mfma_kernel<FIN><<<gemmBlocks, 256, 0, stream>>>(xb, Wt1, dinv, hwb);
    agg_kernel<0><<<aggBlocks, 256, 0, stream>>>(hwb, rowse, csr, dinv, b1, batch,
                                                 nullptr, hb);
    // ---- layer 2 ----
    gemm_mfma_kernel<H><<<gemmBlocks, 256, 0, stream>>>((unsigned short*)hb, Wt2, dinv, hwb);
    agg_kernel<0><<<aggBlocks, 256, 0, stream>>>(hwb, rowse, csr, dinv, b2, batch,
                                                 nullptr, hb);
    // ---- layer 3 ----
    gemm_mfma_kernel<H><<<gemmBlocks, 256, 0, stream>>>((unsigned short*)hb, Wt3, dinv, hwb);
    agg_kernel<0><<<aggBlocks, 256, 0, stream>>>(hwb, rowse, csr, dinv, b3, batch,
                                                 nullptr, hb);
    // ---- layer 4: agg + LDS-reduced pooling (b4 applied in mlp) ----
    gemm_mfma_kernel<H><<<gemmBlocks, 256, 0, stream>>>((unsigned short*)hb, Wt4, dinv, hwb);
    agg_kernel<1><<<aggBlocks, 256, 0, stream>>>(hwb, rowse, csr, dinv, nullptr, batch,
                                                 poolpart, nullptr);

    // ---- final MLP ----
    mlp_kernel<<<1, 1024, 0, stream>>>(poolpart, pcnt, b4, lw1, lb1, lw2, lb2, out);
}

// Round 5
// 318.443 us; speedup vs baseline: 1.9922x; 1.0885x over previous
//
#include <hip/hip_runtime.h>

#define NN 50000
#define NPAD 50048   // rows padded to multiple of 64 for MFMA tiles
#define NE 800000
#define FIN 64
#define H 128
#define NG 16
#define NPART 64         // private pooled-accumulator copies (atomic spreading)
#define NBUCK 196        // buckets of 256 dst nodes
#define BUCK_CAP 4800    // edges per bucket capacity (expected 4096 +- 64)
#define FILLA_BLOCKS 512
#define FILLA_CHUNK 1563  // ceil(NE / FILLA_BLOCKS)
#define CHUNK_U 16       // uints per node per feature-chunk (32 feats)
#define DUMMY NN         // zero pad row used for CSR padding
#define AGG_CH (NPAD / 64) // 782 blocks per chunk (64 nodes/block)
#define ZERO_I4 32768    // int4s to zero: poolpart = 131072 ints
#define PREP_ITEMS (NPAD * FIN + H * FIN + 3 * H * H + ZERO_I4)
#define PREP_BLOCKS ((PREP_ITEMS + 255) / 256)

typedef __bf16 bf16x8 __attribute__((ext_vector_type(8)));
typedef float f32x4 __attribute__((ext_vector_type(4)));
typedef float f32x2 __attribute__((ext_vector_type(2)));
typedef unsigned int u32x4 __attribute__((ext_vector_type(4)));

// ---- helpers ----
__device__ inline unsigned short bf16r(float x) {
    unsigned int u = __float_as_uint(x);
    return (unsigned short)((u + 0x7fffu + ((u >> 16) & 1u)) >> 16);
}
__device__ inline unsigned int pack_bf16x2(float a, float b) {
    return (unsigned int)bf16r(a) | ((unsigned int)bf16r(b) << 16);
}
__device__ inline float bf_lo(unsigned int u) { return __uint_as_float(u << 16); }
__device__ inline float bf_hi(unsigned int u) { return __uint_as_float(u & 0xffff0000u); }

// packed fp32 add: acc(pair) += {lo(u), hi(u)}
__device__ inline void pkadd(f32x2& a, unsigned int u) {
    f32x2 p;
    p.x = bf_lo(u);
    p.y = bf_hi(u);
    asm("v_pk_add_f32 %0, %1, %0" : "+v"(a) : "v"(p));
}

// ====== fillA + prep merged: blocks [0,512) bucket edges; rest convert x/W + zero pool ======
__global__ __launch_bounds__(256) void fillA_prep_kernel(const int* __restrict__ ei,
                                                         int* __restrict__ gcount,
                                                         unsigned int* __restrict__ ebuf,
                                                         const float* __restrict__ x,
                                                         const float* __restrict__ W1,
                                                         const float* __restrict__ W2,
                                                         const float* __restrict__ W3,
                                                         const float* __restrict__ W4,
                                                         unsigned short* __restrict__ xb,
                                                         unsigned short* __restrict__ Wt1,
                                                         unsigned short* __restrict__ Wt2,
                                                         unsigned short* __restrict__ Wt3,
                                                         unsigned short* __restrict__ Wt4,
                                                         int4* __restrict__ zbuf) {
    const int t = threadIdx.x;
    if (blockIdx.x >= FILLA_BLOCKS) {
        // ---- prep part ----
        int e = (blockIdx.x - FILLA_BLOCKS) * 256 + t;
        if (e < NPAD * FIN) {
            int n = e >> 6, k = e & 63;
            unsigned short v = (n < NN) ? bf16r(x[n * FIN + k]) : (unsigned short)0;
            xb[(size_t)(k >> 5) * (NPAD * 32) + n * 32 + (k & 31)] = v;
            return;
        }
        int tt = e - NPAD * FIN;
        if (tt < H * FIN) {
            int n = tt / FIN, k = tt % FIN;
            Wt1[tt] = bf16r(W1[k * H + n]);
            return;
        }
        int u = tt - H * FIN;
        if (u < 3 * H * H) {
            const float* W = W2;
            unsigned short* Wt = Wt2;
            if (u >= 2 * H * H) { W = W4; Wt = Wt4; u -= 2 * H * H; }
            else if (u >= H * H) { W = W3; Wt = Wt3; u -= H * H; }
            int n = u / H, k = u % H;
            Wt[u] = bf16r(W[k * H + n]);
            return;
        }
        int z = u - 3 * H * H;
        if (z < ZERO_I4) zbuf[z] = make_int4(0, 0, 0, 0);  // zero pool partials
        return;
    }
    // ---- fillA part: histogram into 196 buckets of 256 nodes ----
    __shared__ int hist[256];
    __shared__ int base[256];
    hist[t] = 0;
    __syncthreads();
    const int e0 = blockIdx.x * FILLA_CHUNK;
    const int e1 = min(e0 + FILLA_CHUNK, NE);
    for (int e = e0 + t; e < e1; e += 256)
        atomicAdd(&hist[ei[NE + e] >> 8], 1);
    __syncthreads();
    {
        int h = hist[t];
        base[t] = h ? atomicAdd(&gcount[t], h) : 0;
    }
    __syncthreads();
    for (int e = e0 + t; e < e1; e += 256) {
        int d = ei[NE + e];
        int s = ei[e];
        int b = d >> 8;
        int pos = atomicAdd(&base[b], 1);
        ebuf[b * BUCK_CAP + pos] = (unsigned int)s | ((unsigned int)d << 16);
    }
}

// fillB (fused hist+scan+scatter), 196 blocks, 1 node per thread.
// Also accumulates per-graph node counts (pcnt) for the pooled mean.
__global__ __launch_bounds__(256) void fillB_kernel(const unsigned int* __restrict__ ebuf,
                                                    const int* __restrict__ gcount,
                                                    int* __restrict__ galloc,
                                                    int* __restrict__ pcnt,
                                                    const int* __restrict__ batch,
                                                    int2* __restrict__ rowse,
                                                    float* __restrict__ dinv,
                                                    unsigned short* __restrict__ csr) {
    __shared__ int lh[256];
    __shared__ int lsum[256];
    __shared__ int lcur[256];
    __shared__ int lgc[16];
    __shared__ int base_s;
    const int b = blockIdx.x, t = threadIdx.x;
    const int n0 = b * 256;
    lh[t] = 0;
    if (t < 16) lgc[t] = 0;
    __syncthreads();
    const int ne = gcount[b];
    const unsigned int* __restrict__ eb = ebuf + b * BUCK_CAP;
    for (int i = t; i < ne; i += 256)
        atomicAdd(&lh[(int)(eb[i] >> 16) - n0], 1);
    __syncthreads();
    const int c = lh[t];
    const int p = (c + 7) & ~7;
    const int n = n0 + t;
    if (n < NN) atomicAdd(&lgc[batch[n]], 1);
    lsum[t] = p;
    __syncthreads();
    if (t < 16 && lgc[t]) atomicAdd(&pcnt[t], lgc[t]);
    for (int off = 1; off < 256; off <<= 1) {
        int u = (t >= off) ? lsum[t - off] : 0;
        __syncthreads();
        lsum[t] += u;
        __syncthreads();
    }
    if (t == 255) base_s = atomicAdd(galloc, lsum[255]);
    const int excl = t ? lsum[t - 1] : 0;
    __syncthreads();
    const int st = base_s + excl;
    if (n < NN) {
        rowse[n] = make_int2(st, st + p);
        dinv[n] = rsqrtf((float)c + 1.0f);  // +1 self-loop
    } else if (n < NPAD) {
        rowse[n] = make_int2(0, 0);
        dinv[n] = 0.0f;
    }
    lcur[t] = st;
    __syncthreads();
    for (int i = t; i < ne; i += 256) {
        unsigned int u = eb[i];
        int pos = atomicAdd(&lcur[(int)(u >> 16) - n0], 1);
        csr[pos] = (unsigned short)(u & 0xFFFFu);
    }
    __syncthreads();
    for (int k = st + c; k < st + p; k++) csr[k] = (unsigned short)DUMMY;
}

// ===== MFMA GEMM (chunked in/out): hw' = (h @ W) * dinv[row], bf16 out =====
#define LSTRIDE 130
template <int K>
__global__ __launch_bounds__(256) void gemm_mfma_kernel(const unsigned short* __restrict__ hb,
                                                        const unsigned short* __restrict__ Wt,
                                                        const float* __restrict__ dinv,
                                                        unsigned int* __restrict__ outu) {
    __shared__ float ls[64 * LSTRIDE];  // ~33 KB
    const int wave = threadIdx.x >> 6, lane = threadIdx.x & 63;
    const int m15 = lane & 15, quad = lane >> 4;
    const int row0 = blockIdx.x * 64;
    const int arow = row0 + wave * 16 + m15;

    bf16x8 a[K / 32];
#pragma unroll
    for (int ks = 0; ks < K / 32; ks++)
        a[ks] = *(const bf16x8*)&hb[(size_t)ks * (NPAD * 32) + arow * 32 + quad * 8];

    const int lrow = wave * 16 + quad * 4;
    float dv[4];
#pragma unroll
    for (int r = 0; r < 4; r++) dv[r] = dinv[row0 + lrow + r];

#pragma unroll
    for (int ct = 0; ct < 8; ct++) {
        f32x4 acc = {0.f, 0.f, 0.f, 0.f};
#pragma unroll
        for (int ks = 0; ks < K / 32; ks++) {
            bf16x8 b = *(const bf16x8*)&Wt[(ct * 16 + m15) * K + ks * 32 + quad * 8];
            acc = __builtin_amdgcn_mfma_f32_16x16x32_bf16(a[ks], b, acc, 0, 0, 0);
        }
#pragma unroll
        for (int r = 0; r < 4; r++)
            ls[(lrow + r) * LSTRIDE + ct * 16 + m15] = acc[r] * dv[r];
    }
    __syncthreads();

#pragma unroll
    for (int k = 0; k < 4; k++) {
        int idx = threadIdx.x + 256 * k;
        int c = idx >> 8, row = (idx >> 2) & 63, q = idx & 3;
        const float* p = &ls[row * LSTRIDE + c * 32 + q * 8];
        uint4 o;
        o.x = pack_bf16x2(p[0], p[1]);
        o.y = pack_bf16x2(p[2], p[3]);
        o.z = pack_bf16x2(p[4], p[5]);
        o.w = pack_bf16x2(p[6], p[7]);
        *(uint4*)&outu[(size_t)c * (NPAD * CHUNK_U) + (size_t)(row0 + row) * CHUNK_U + q * 4] = o;
    }
}

// ====== feature-chunked gather aggregation ======
// XCD-affinity: dispatch round-robins blocks over 8 XCDs (xcd = blockIdx%8), so
// chunk = (b&7)>>1 pins each chunk's 3.2 MB gather slice into 2 XCDs' L2.
// 4 lanes per node, uint4 gathers, edge loop unrolled x2 (16 gathers in flight).
// MODE 0: relu(x*dinv + bias) -> bf16 nontemporal store (don't evict the slice).
// MODE 1 (layer 4): per-wave shfl butterfly over 16 nodes -> ~32 atomics/wave,
//   no __syncthreads (block-wide max-degree coupling cost ~11 us in round 3).
template <int MODE>
__global__ __launch_bounds__(256) void agg_kernel(const unsigned int* __restrict__ hwc,
                                                  const int2* __restrict__ rowse,
                                                  const unsigned short* __restrict__ csr,
                                                  const float* __restrict__ dinv,
                                                  const float* __restrict__ bias,
                                                  const int* __restrict__ batch,
                                                  float* __restrict__ poolpart,
                                                  unsigned int* __restrict__ outc) {
    const int b = blockIdx.x;
    const int chunk = (b & 7) >> 1;              // XCD pair -> chunk
    const int nb = (b >> 3) * 2 + (b & 1);       // within-chunk node-block
    const int g = threadIdx.x & 3;               // lane's uint-quad within the chunk
    const int n = nb * 64 + (threadIdx.x >> 2);  // node (64 per block, incl. pad rows)
    const int u0 = g * 4;
    const unsigned int* __restrict__ slice = hwc + (size_t)chunk * (NPAD * CHUNK_U);

    uint4 sv = *(const uint4*)&slice[n * CHUNK_U + u0];  // self-loop term
    f32x2 a0 = {bf_lo(sv.x), bf_hi(sv.x)};
    f32x2 a1 = {bf_lo(sv.y), bf_hi(sv.y)};
    f32x2 a2 = {bf_lo(sv.z), bf_hi(sv.z)};
    f32x2 a3 = {bf_lo(sv.w), bf_hi(sv.w)};

    const int2 se = rowse[n];  // start/end, both multiples of 8
    int i = se.x;
    for (; i + 16 <= se.y; i += 16) {  // unroll x2: 16 gathers outstanding
        uint4 c0 = *(const uint4*)&csr[i];
        uint4 c1 = *(const uint4*)&csr[i + 8];
        int s0 = c0.x & 0xFFFF, s1 = c0.x >> 16;
        int s2 = c0.y & 0xFFFF, s3 = c0.y >> 16;
        int s4 = c0.z & 0xFFFF, s5 = c0.z >> 16;
        int s6 = c0.w & 0xFFFF, s7 = c0.w >> 16;
        int t0 = c1.x & 0xFFFF, t1 = c1.x >> 16;
        int t2 = c1.y & 0xFFFF, t3 = c1.y >> 16;
        int t4 = c1.z & 0xFFFF, t5 = c1.z >> 16;
        int t6 = c1.w & 0xFFFF, t7 = c1.w >> 16;
        uint4 v0 = *(const uint4*)&slice[s0 * CHUNK_U + u0];
        uint4 v1 = *(const uint4*)&slice[s1 * CHUNK_U + u0];
        uint4 v2 = *(const uint4*)&slice[s2 * CHUNK_U + u0];
        uint4 v3 = *(const uint4*)&slice[s3 * CHUNK_U + u0];
        uint4 v4 = *(const uint4*)&slice[s4 * CHUNK_U + u0];
        uint4 v5 = *(const uint4*)&slice[s5 * CHUNK_U + u0];
        uint4 v6 = *(const uint4*)&slice[s6 * CHUNK_U + u0];
        uint4 v7 = *(const uint4*)&slice[s7 * CHUNK_U + u0];
        uint4 w0 = *(const uint4*)&slice[t0 * CHUNK_U + u0];
        uint4 w1 = *(const uint4*)&slice[t1 * CHUNK_U + u0];
        uint4 w2 = *(const uint4*)&slice[t2 * CHUNK_U + u0];
        uint4 w3 = *(const uint4*)&slice[t3 * CHUNK_U + u0];
        uint4 w4 = *(const uint4*)&slice[t4 * CHUNK_U + u0];
        uint4 w5 = *(const uint4*)&slice[t5 * CHUNK_U + u0];
        uint4 w6 = *(const uint4*)&slice[t6 * CHUNK_U + u0];
        uint4 w7 = *(const uint4*)&slice[t7 * CHUNK_U + u0];
        pkadd(a0, v0.x); pkadd(a1, v0.y); pkadd(a2, v0.z); pkadd(a3, v0.w);
        pkadd(a0, v1.x); pkadd(a1, v1.y); pkadd(a2, v1.z); pkadd(a3, v1.w);
        pkadd(a0, v2.x); pkadd(a1, v2.y); pkadd(a2, v2.z); pkadd(a3, v2.w);
        pkadd(a0, v3.x); pkadd(a1, v3.y); pkadd(a2, v3.z); pkadd(a3, v3.w);
        pkadd(a0, v4.x); pkadd(a1, v4.y); pkadd(a2, v4.z); pkadd(a3, v4.w);
        pkadd(a0, v5.x); pkadd(a1, v5.y); pkadd(a2, v5.z); pkadd(a3, v5.w);
        pkadd(a0, v6.x); pkadd(a1, v6.y); pkadd(a2, v6.z); pkadd(a3, v6.w);
        pkadd(a0, v7.x); pkadd(a1, v7.y); pkadd(a2, v7.z); pkadd(a3, v7.w);
        pkadd(a0, w0.x); pkadd(a1, w0.y); pkadd(a2, w0.z); pkadd(a3, w0.w);
        pkadd(a0, w1.x); pkadd(a1, w1.y); pkadd(a2, w1.z); pkadd(a3, w1.w);
        pkadd(a0, w2.x); pkadd(a1, w2.y); pkadd(a2, w2.z); pkadd(a3, w2.w);
        pkadd(a0, w3.x); pkadd(a1, w3.y); pkadd(a2, w3.z); pkadd(a3, w3.w);
        pkadd(a0, w4.x); pkadd(a1, w4.y); pkadd(a2, w4.z); pkadd(a3, w4.w);
        pkadd(a0, w5.x); pkadd(a1, w5.y); pkadd(a2, w5.z); pkadd(a3, w5.w);
        pkadd(a0, w6.x); pkadd(a1, w6.y); pkadd(a2, w6.z); pkadd(a3, w6.w);
        pkadd(a0, w7.x); pkadd(a1, w7.y); pkadd(a2, w7.z); pkadd(a3, w7.w);
    }
    if (i < se.y) {  // remainder is exactly one 8-group (rows padded to x8)
        uint4 c = *(const uint4*)&csr[i];
        int s0 = c.x & 0xFFFF, s1 = c.x >> 16;
        int s2 = c.y & 0xFFFF, s3 = c.y >> 16;
        int s4 = c.z & 0xFFFF, s5 = c.z >> 16;
        int s6 = c.w & 0xFFFF, s7 = c.w >> 16;
        uint4 v0 = *(const uint4*)&slice[s0 * CHUNK_U + u0];
        uint4 v1 = *(const uint4*)&slice[s1 * CHUNK_U + u0];
        uint4 v2 = *(const uint4*)&slice[s2 * CHUNK_U + u0];
        uint4 v3 = *(const uint4*)&slice[s3 * CHUNK_U + u0];
        uint4 v4 = *(const uint4*)&slice[s4 * CHUNK_U + u0];
        uint4 v5 = *(const uint4*)&slice[s5 * CHUNK_U + u0];
        uint4 v6 = *(const uint4*)&slice[s6 * CHUNK_U + u0];
        uint4 v7 = *(const uint4*)&slice[s7 * CHUNK_U + u0];
        pkadd(a0, v0.x); pkadd(a1, v0.y); pkadd(a2, v0.z); pkadd(a3, v0.w);
        pkadd(a0, v1.x); pkadd(a1, v1.y); pkadd(a2, v1.z); pkadd(a3, v1.w);
        pkadd(a0, v2.x); pkadd(a1, v2.y); pkadd(a2, v2.z); pkadd(a3, v2.w);
        pkadd(a0, v3.x); pkadd(a1, v3.y); pkadd(a2, v3.z); pkadd(a3, v3.w);
        pkadd(a0, v4.x); pkadd(a1, v4.y); pkadd(a2, v4.z); pkadd(a3, v4.w);
        pkadd(a0, v5.x); pkadd(a1, v5.y); pkadd(a2, v5.z); pkadd(a3, v5.w);
        pkadd(a0, v6.x); pkadd(a1, v6.y); pkadd(a2, v6.z); pkadd(a3, v6.w);
        pkadd(a0, v7.x); pkadd(a1, v7.y); pkadd(a2, v7.z); pkadd(a3, v7.w);
    }

    const float d = dinv[n];
    if (MODE == 1) {
        a0 *= d; a1 *= d; a2 *= d; a3 *= d;
        const int lane = threadIdx.x & 63;
        const int wv = threadIdx.x >> 6;
        const int gb = batch[min(n, NN - 1)];   // pads clamp to last graph; d=0 zeroes them
        const int gfirst = __shfl(gb, 0);
        const bool uni = (__shfl(gb, 63) == gfirst);
        float* __restrict__ pp = poolpart + (((b << 2) + wv) & (NPART - 1)) * (NG * H);
        if (uni) {
#pragma unroll
            for (int m = 4; m <= 32; m <<= 1) {  // butterfly over the wave's 16 nodes
                a0.x += __shfl_xor(a0.x, m); a0.y += __shfl_xor(a0.y, m);
                a1.x += __shfl_xor(a1.x, m); a1.y += __shfl_xor(a1.y, m);
                a2.x += __shfl_xor(a2.x, m); a2.y += __shfl_xor(a2.y, m);
                a3.x += __shfl_xor(a3.x, m); a3.y += __shfl_xor(a3.y, m);
            }
            if (lane < 4) {  // lane == its quad g
                float* q = pp + gfirst * H + chunk * 32 + lane * 8;
                atomicAdd(&q[0], a0.x); atomicAdd(&q[1], a0.y);
                atomicAdd(&q[2], a1.x); atomicAdd(&q[3], a1.y);
                atomicAdd(&q[4], a2.x); atomicAdd(&q[5], a2.y);
                atomicAdd(&q[6], a3.x); atomicAdd(&q[7], a3.y);
            }
        } else if (n < NN) {  // rare graph-boundary wave: per-node atomics
            float* q = pp + gb * H + chunk * 32 + g * 8;
            atomicAdd(&q[0], a0.x); atomicAdd(&q[1], a0.y);
            atomicAdd(&q[2], a1.x); atomicAdd(&q[3], a1.y);
            atomicAdd(&q[4], a2.x); atomicAdd(&q[5], a2.y);
            atomicAdd(&q[6], a3.x); atomicAdd(&q[7], a3.y);
        }
        return;
    }
    const float2* bp = (const float2*)bias + chunk * CHUNK_U + u0;
    float2 q0 = bp[0], q1 = bp[1], q2 = bp[2], q3 = bp[3];
    u32x4 o;
    o[0] = pack_bf16x2(fmaxf(a0.x * d + q0.x, 0.f), fmaxf(a0.y * d + q0.y, 0.f));
    o[1] = pack_bf16x2(fmaxf(a1.x * d + q1.x, 0.f), fmaxf(a1.y * d + q1.y, 0.f));
    o[2] = pack_bf16x2(fmaxf(a2.x * d + q2.x, 0.f), fmaxf(a2.y * d + q2.y, 0.f));
    o[3] = pack_bf16x2(fmaxf(a3.x * d + q3.x, 0.f), fmaxf(a3.y * d + q3.y, 0.f));
    __builtin_nontemporal_store(
        o, (u32x4*)&outc[(size_t)chunk * (NPAD * CHUNK_U) + (size_t)n * CHUNK_U + u0]);
}

// ============ final MLP (single block): reduce NPART copies, +b4, then GEMMs ============
__global__ __launch_bounds__(1024) void mlp_kernel(const float* __restrict__ poolpart,
                                                   const int* __restrict__ pcnt,
                                                   const float* __restrict__ b4,
                                                   const float* __restrict__ lw1,
                                                   const float* __restrict__ lb1,
                                                   const float* __restrict__ lw2,
                                                   const float* __restrict__ lb2,
                                                   float* __restrict__ out) {
    __shared__ float mean_s[NG * H];
    __shared__ float cnt_s[NG];
    __shared__ float hid_s[NG * 64];
    int tid = threadIdx.x;
    if (tid < NG) cnt_s[tid] = fmaxf((float)pcnt[tid], 1.0f);
    __syncthreads();
    for (int i = tid; i < NG * H; i += 1024) {
        float s = 0.f;
        for (int p = 0; p < NPART; p++) s += poolpart[p * (NG * H) + i];
        mean_s[i] = s / cnt_s[i >> 7] + b4[i & (H - 1)];
    }
    __syncthreads();
    {
        int g = tid >> 6, j = tid & 63;
        float acc = lb1[j];
        for (int f = 0; f < H; f++) acc += mean_s[g * H + f] * lw1[f * 64 + j];
        hid_s[g * 64 + j] = fmaxf(acc, 0.f);
    }
    __syncthreads();
    if (tid < 32) {
        int g = tid >> 1, c = tid & 1;
        float acc = lb2[c];
        for (int j = 0; j < 64; j++) acc += hid_s[g * 64 + j] * lw2[j * 2 + c];
        out[g * 2 + c] = acc;
    }
}

extern "C" void kernel_launch(void* const* d_in, const int* in_sizes, int n_in,
                              void* d_out, int out_size, void* d_ws, size_t ws_size,
                              hipStream_t stream) {
    const float* x = (const float*)d_in[0];
    const int* ei = (const int*)d_in[1];
    const int* batch = (const int*)d_in[2];
    const float* W1 = (const float*)d_in[3];
    const float* b1 = (const float*)d_in[4];
    const float* W2 = (const float*)d_in[5];
    const float* b2 = (const float*)d_in[6];
    const float* W3 = (const float*)d_in[7];
    const float* b3 = (const float*)d_in[8];
    const float* W4 = (const float*)d_in[9];
    const float* b4 = (const float*)d_in[10];
    const float* lw1 = (const float*)d_in[11];
    const float* lb1 = (const float*)d_in[12];
    const float* lw2 = (const float*)d_in[13];
    const float* lb2 = (const float*)d_in[14];
    float* out = (float*)d_out;

    // workspace layout (4-byte units; sizes annotated in ints); ~39.5 MB
    int* wsi = (int*)d_ws;
    int* gcount = wsi;                                      // @0        256
    int* galloc = wsi + 256;                                // @256      1
    int* pcnt = wsi + 280;                                  // @280      16 (zeroed to 512)
    float* poolpart = (float*)(wsi + 512);                  // @512      131072 (NPART*NG*H)
    int2* rowse = (int2*)(wsi + 131584);                    // @131584   100096 (NPAD int2)
    unsigned short* csr = (unsigned short*)(wsi + 231680);  // @231680   600000 (1.2M ushorts)
    float* dinv = (float*)(wsi + 831680);                   // @831680   50048
    unsigned short* Wt1 = (unsigned short*)(wsi + 881728);  // @881728   4096 (8192 shorts)
    unsigned short* Wt2 = (unsigned short*)(wsi + 885824);  // @885824   8192 (16384 shorts)
    unsigned short* Wt3 = (unsigned short*)(wsi + 894016);  // @894016   8192
    unsigned short* Wt4 = (unsigned short*)(wsi + 902208);  // @902208   8192
    unsigned short* xb = (unsigned short*)(wsi + 910400);   // @910400   1601536 (NPAD*64 shorts)
    unsigned int* hb = (unsigned int*)(wsi + 2511936);      // @2511936  3203072 (NPAD*64 uints)
    unsigned int* hwb = (unsigned int*)(wsi + 5715008);     // @5715008  3203072
    unsigned int* ebuf = (unsigned int*)(wsi + 8918080);    // @8918080  940800 -> ends 9858880

    const int gemmBlocks = NPAD / 64;          // 782
    const int aggBlocks = 4 * AGG_CH;          // 3128 = 8 * 391, XCD-affine remap

    // ---- zero control vars (tiny); pool partials zeroed inside prep ----
    hipMemsetAsync(wsi, 0, 512 * sizeof(int), stream);
    fillA_prep_kernel<<<FILLA_BLOCKS + PREP_BLOCKS, 256, 0, stream>>>(
        ei, gcount, ebuf, x, W1, W2, W3, W4, xb, Wt1, Wt2, Wt3, Wt4, (int4*)poolpart);
    fillB_kernel<<<NBUCK, 256, 0, stream>>>(ebuf, gcount, galloc, pcnt, batch,
                                            rowse, dinv, csr);

    // ---- layer 1 ----
    gemm_mfma_kernel<FIN><<<gemmBlocks, 256, 0, stream>>>(xb, Wt1, dinv, hwb);
    agg_kernel<0><<<aggBlocks, 256, 0, stream>>>(hwb, rowse, csr, dinv, b1, batch,
                                                 nullptr, hb);
    // ---- layer 2 ----
    gemm_mfma_kernel<H><<<gemmBlocks, 256, 0, stream>>>((unsigned short*)hb, Wt2, dinv, hwb);
    agg_kernel<0><<<aggBlocks, 256, 0, stream>>>(hwb, rowse, csr, dinv, b2, batch,
                                                 nullptr, hb);
    // ---- layer 3 ----
    gemm_mfma_kernel<H><<<gemmBlocks, 256, 0, stream>>>((unsigned short*)hb, Wt3, dinv, hwb);
    agg_kernel<0><<<aggBlocks, 256, 0, stream>>>(hwb, rowse, csr, dinv, b3, batch,
                                                 nullptr, hb);
    // ---- layer 4: agg + wave-reduced pooling (b4 applied in mlp) ----
    gemm_mfma_kernel<H><<<gemmBlocks, 256, 0, stream>>>((unsigned short*)hb, Wt4, dinv, hwb);
    agg_kernel<1><<<aggBlocks, 256, 0, stream>>>(hwb, rowse, csr, dinv, nullptr, batch,
                                                 poolpart, nullptr);

    // ---- final MLP ----
    mlp_kernel<<<1, 1024, 0, stream>>>(poolpart, pcnt, b4, lw1, lb1, lw2, lb2, out);
}